// Round 7
// baseline (190.808 us; speedup 1.0000x reference)
//
#include <hip/hip_runtime.h>
#include <hip/hip_bf16.h>

typedef short s16x8 __attribute__((ext_vector_type(8)));
typedef float f32x4 __attribute__((ext_vector_type(4)));

#define LOG2E_2 2.8853900817779268f  // 2*log2(e)

__device__ __forceinline__ float fexp2(float x){ return __builtin_amdgcn_exp2f(x); }
__device__ __forceinline__ float frcp (float x){ return __builtin_amdgcn_rcpf(x); }
// tanh(v) = 1 - 2/(1+exp(2v))
__device__ __forceinline__ float ftanh(float v){
    return 1.0f - 2.0f * frcp(1.0f + fexp2(LOG2E_2 * v));
}
__device__ __forceinline__ unsigned short f2bf(float v){
    __hip_bfloat16 h = __float2bfloat16(v);
    return __builtin_bit_cast(unsigned short, h);
}
__device__ __forceinline__ float bf2f(unsigned short u){
    return __bfloat162float(__builtin_bit_cast(__hip_bfloat16, u));
}
__device__ __forceinline__ f32x4 mfma32(s16x8 a, s16x8 b, f32x4 c){
    return __builtin_amdgcn_mfma_f32_16x16x32_bf16(a, b, c, 0, 0, 0);
}

// ---------- prep_all: one launch does all reformatting ----------
__global__ __launch_bounds__(256) void prep_all(
    const float* __restrict__ l0, const float* __restrict__ l1,
    const float* __restrict__ Wfoh, const float* __restrict__ Wfom,
    const float* __restrict__ W2,
    unsigned short* __restrict__ xs_hi, unsigned short* __restrict__ xs_lo,
    unsigned short* __restrict__ w1t_hi, unsigned short* __restrict__ w1t_lo,
    unsigned short* __restrict__ w2t_hi, unsigned short* __restrict__ w2t_lo)
{
    const int b = blockIdx.x;
    const int t = threadIdx.x;
    if (b < 512) {
        int idx = (b*256 + t) * 4;
        int r = idx >> 9, c = idx & 511;
        float4 v = (c < 256) ? *(const float4*)(l0 + r*256 + c)
                             : *(const float4*)(l1 + r*256 + (c - 256));
        ushort4 h, l;
        h.x = f2bf(v.x); l.x = f2bf(v.x - bf2f(h.x));
        h.y = f2bf(v.y); l.y = f2bf(v.y - bf2f(h.y));
        h.z = f2bf(v.z); l.z = f2bf(v.z - bf2f(h.z));
        h.w = f2bf(v.w); l.w = f2bf(v.w - bf2f(h.w));
        *(ushort4*)(xs_hi + idx) = h;
        *(ushort4*)(xs_lo + idx) = l;
        return;
    }
    __shared__ float F[32][33];
    int k0, n0, K;
    const float *srcA, *srcB;
    int splitN, lda;
    unsigned short *dhi, *dlo;
    if (b < 1024) {
        int tb = b - 512;
        k0 = (tb & 15) * 32; n0 = (tb >> 4) * 32; K = 512;
        srcA = Wfoh; srcB = Wfom; splitN = 512; lda = 512;
        dhi = w1t_hi; dlo = w1t_lo;
    } else {
        int tb = b - 1024;
        k0 = (tb & 31) * 32; n0 = (tb >> 5) * 32; K = 1024;
        srcA = W2; srcB = W2; splitN = 1 << 30; lda = 256;
        dhi = w2t_hi; dlo = w2t_lo;
    }
    {
        int kk = t >> 3, n4 = (t & 7) * 4;
        int n = n0 + n4;
        const float* s = (n < splitN) ? (srcA + (k0+kk)*lda + n)
                                      : (srcB + (k0+kk)*lda + (n - splitN));
        float4 v = *(const float4*)s;
        F[kk][n4+0] = v.x; F[kk][n4+1] = v.y; F[kk][n4+2] = v.z; F[kk][n4+3] = v.w;
    }
    __syncthreads();
    {
        int nn = t >> 3, k4 = (t & 7) * 4;
        ushort4 h, l;
        float v0 = F[k4+0][nn]; h.x = f2bf(v0); l.x = f2bf(v0 - bf2f(h.x));
        float v1 = F[k4+1][nn]; h.y = f2bf(v1); l.y = f2bf(v1 - bf2f(h.y));
        float v2 = F[k4+2][nn]; h.z = f2bf(v2); l.z = f2bf(v2 - bf2f(h.z));
        float v3 = F[k4+3][nn]; h.w = f2bf(v3); l.w = f2bf(v3 - bf2f(h.w));
        *(ushort4*)(dhi + (n0+nn)*K + k0 + k4) = h;
        *(ushort4*)(dlo + (n0+nn)*K + k0 + k4) = l;
    }
}

// ---------- K1 (x4 AMPLIFIED for profiling visibility) ----------
// hv = tanh(x @ W1 + cb). Same structure as round 6; the whole K-loop repeats
// 4x with accumulator reset -> identical output, 4x duration, surfaces full
// rocprof counters above the 43us harness-fill cutoff.
__global__ __launch_bounds__(512) void k1_mfma(
    const unsigned short* __restrict__ xs_hi, const unsigned short* __restrict__ xs_lo,
    const unsigned short* __restrict__ w1t_hi, const unsigned short* __restrict__ w1t_lo,
    const float* __restrict__ cb, unsigned int* __restrict__ hv)
{
    __shared__ unsigned short Ah[2][64][40], Al[2][64][40], Bh[2][64][40], Bl[2][64][40];
    const int t = threadIdx.x;
    const int bx = blockIdx.x & 15, by = blockIdx.x >> 4;
    const int r0 = by*64, c0 = bx*64;
    const int w = t >> 6, lane = t & 63;
    const int m = lane & 15, quad = lane >> 4;
    const int ms = (w & 3)*16, ns = (w >> 2)*32;

    const int srow = (t & 255) >> 2;
    const int sk   = (t & 3) * 8;
    const bool isA = (t < 256);
    const unsigned short* ghi = isA ? (xs_hi + (r0+srow)*512 + sk) : (w1t_hi + (c0+srow)*512 + sk);
    const unsigned short* glo = isA ? (xs_lo + (r0+srow)*512 + sk) : (w1t_lo + (c0+srow)*512 + sk);

    f32x4 acc0, acc1;

    for (int rep = 0; rep < 4; ++rep) {
        acc0 = (f32x4){0,0,0,0};
        acc1 = (f32x4){0,0,0,0};

        uint4 rh[2], rl[2];
        rh[0] = *(const uint4*)(ghi);      rl[0] = *(const uint4*)(glo);
        rh[1] = *(const uint4*)(ghi + 32); rl[1] = *(const uint4*)(glo + 32);

        __syncthreads();
        if (isA) { *(uint4*)&Ah[0][srow][sk] = rh[0]; *(uint4*)&Al[0][srow][sk] = rl[0]; }
        else     { *(uint4*)&Bh[0][srow][sk] = rh[0]; *(uint4*)&Bl[0][srow][sk] = rl[0]; }
        __syncthreads();

        for (int c = 0; c < 16; ++c) {
            const int s0 = c & 1, s1 = (c+1) & 1;
            if (c + 2 < 16) {
                rh[s0] = *(const uint4*)(ghi + (c+2)*32);
                rl[s0] = *(const uint4*)(glo + (c+2)*32);
            }
            {
                const int ko = quad*8;
                s16x8 ah  = *(const s16x8*)&Ah[s0][ms+m][ko];
                s16x8 al  = *(const s16x8*)&Al[s0][ms+m][ko];
                s16x8 b0h = *(const s16x8*)&Bh[s0][ns+m][ko];
                s16x8 b0l = *(const s16x8*)&Bl[s0][ns+m][ko];
                s16x8 b1h = *(const s16x8*)&Bh[s0][ns+16+m][ko];
                s16x8 b1l = *(const s16x8*)&Bl[s0][ns+16+m][ko];
                acc0 = mfma32(ah, b0h, acc0);
                acc0 = mfma32(ah, b0l, acc0);
                acc0 = mfma32(al, b0h, acc0);
                acc1 = mfma32(ah, b1h, acc1);
                acc1 = mfma32(ah, b1l, acc1);
                acc1 = mfma32(al, b1h, acc1);
            }
            if (c + 1 < 16) {
                if (isA) { *(uint4*)&Ah[s1][srow][sk] = rh[s1]; *(uint4*)&Al[s1][srow][sk] = rl[s1]; }
                else     { *(uint4*)&Bh[s1][srow][sk] = rh[s1]; *(uint4*)&Bl[s1][srow][sk] = rl[s1]; }
                __syncthreads();
            }
        }
    }

    #pragma unroll
    for (int nt = 0; nt < 2; ++nt) {
        f32x4 a = nt ? acc1 : acc0;
        const int col = c0 + ns + nt*16 + m;
        const float bias = cb[col];
        #pragma unroll
        for (int reg = 0; reg < 4; ++reg) {
            const int row = r0 + ms + quad*4 + reg;
            float v = ftanh(a[reg] + bias);
            unsigned short h = f2bf(v);
            unsigned short l = f2bf(v - bf2f(h));
            hv[row*1024 + col] = (unsigned int)h | ((unsigned int)l << 16);
        }
    }
}

// ---------- K2: P[1024][512] = exp2(LOG2E_2*(hv_half @ W2_half + bias)) ----------
__global__ __launch_bounds__(512) void k2_mfma(
    const unsigned int* __restrict__ hv,
    const unsigned short* __restrict__ w2t_hi, const unsigned short* __restrict__ w2t_lo,
    const float* __restrict__ h2b, float* __restrict__ P)
{
    __shared__ unsigned short Ah[2][64][40], Al[2][64][40], Bh[2][32][40], Bl[2][32][40];
    const int t = threadIdx.x;
    const int bx = blockIdx.x & 15, by = blockIdx.x >> 4;
    const int r0 = by*64, c0 = bx*32;
    const int half = (c0 >= 256) ? 1 : 0;
    const int ho = half * 512;
    const int nw = c0 & 255;
    const int w = t >> 6, lane = t & 63;
    const int m = lane & 15, quad = lane >> 4;
    const int ms = (w & 3)*16, ns = (w >> 2)*16;

    const int arow = t >> 3, akk = (t & 7) * 4;
    const int brow = (t & 127) >> 2, bkk = (t & 3) * 8;
    const bool doBh = (t < 128), doBl = (t >= 128 && t < 256);

    const unsigned int*   gA  = hv + (r0+arow)*1024 + ho + akk;
    const unsigned short* gBh = w2t_hi + (nw+brow)*1024 + ho + bkk;
    const unsigned short* gBl = w2t_lo + (nw+brow)*1024 + ho + bkk;

    uint4 ra[2], rb[2];
    ra[0] = *(const uint4*)(gA);
    ra[1] = *(const uint4*)(gA + 32);
    rb[0] = doBh ? *(const uint4*)(gBh) : (doBl ? *(const uint4*)(gBl) : make_uint4(0,0,0,0));
    rb[1] = doBh ? *(const uint4*)(gBh + 32) : (doBl ? *(const uint4*)(gBl + 32) : make_uint4(0,0,0,0));

    f32x4 acc = {0,0,0,0};

    {
        ushort4 h = make_ushort4(ra[0].x & 0xffff, ra[0].y & 0xffff, ra[0].z & 0xffff, ra[0].w & 0xffff);
        ushort4 l = make_ushort4(ra[0].x >> 16,    ra[0].y >> 16,    ra[0].z >> 16,    ra[0].w >> 16);
        *(ushort4*)&Ah[0][arow][akk] = h;
        *(ushort4*)&Al[0][arow][akk] = l;
        if (doBh) *(uint4*)&Bh[0][brow][bkk] = rb[0];
        if (doBl) *(uint4*)&Bl[0][brow][bkk] = rb[0];
    }
    __syncthreads();

    for (int c = 0; c < 16; ++c) {
        const int s0 = c & 1, s1 = (c+1) & 1;
        if (c + 2 < 16) {
            ra[s0] = *(const uint4*)(gA + (c+2)*32);
            if (doBh) rb[s0] = *(const uint4*)(gBh + (c+2)*32);
            if (doBl) rb[s0] = *(const uint4*)(gBl + (c+2)*32);
        }
        {
            const int ko = quad*8;
            s16x8 ah = *(const s16x8*)&Ah[s0][ms+m][ko];
            s16x8 al = *(const s16x8*)&Al[s0][ms+m][ko];
            s16x8 bh = *(const s16x8*)&Bh[s0][ns+m][ko];
            s16x8 bl = *(const s16x8*)&Bl[s0][ns+m][ko];
            acc = mfma32(ah, bh, acc);
            acc = mfma32(ah, bl, acc);
            acc = mfma32(al, bh, acc);
        }
        if (c + 1 < 16) {
            ushort4 h = make_ushort4(ra[s1].x & 0xffff, ra[s1].y & 0xffff, ra[s1].z & 0xffff, ra[s1].w & 0xffff);
            ushort4 l = make_ushort4(ra[s1].x >> 16,    ra[s1].y >> 16,    ra[s1].z >> 16,    ra[s1].w >> 16);
            *(ushort4*)&Ah[s1][arow][akk] = h;
            *(ushort4*)&Al[s1][arow][akk] = l;
            if (doBh) *(uint4*)&Bh[s1][brow][bkk] = rb[s1];
            if (doBl) *(uint4*)&Bl[s1][brow][bkk] = rb[s1];
            __syncthreads();
        }
    }

    const int col = c0 + ns + m;
    const float bias = half ? 0.0f : h2b[col];
    #pragma unroll
    for (int reg = 0; reg < 4; ++reg) {
        const int row = r0 + ms + quad*4 + reg;
        P[row*512 + col] = fexp2((acc[reg] + bias) * LOG2E_2);
    }
}

// ---------- K3 (round-4 version, best known) ----------
__global__ __launch_bounds__(256) void k3_pairwise(
    const float* __restrict__ P, const float* __restrict__ w,
    const float* __restrict__ ob, float* __restrict__ out)
{
    __shared__ float As[32][68];
    __shared__ float Bs[64][34];
    __shared__ float wls[256];
    const int tid = threadIdx.x;
    const int tx = tid & 15;
    const int ty = tid >> 4;
    const int i0 = blockIdx.y * 32, j0 = blockIdx.x * 32;

    wls[tid] = w[tid];

    int rr0 = tid >> 4,         c40 = (tid & 15) * 4;
    int rr1 = (tid + 256) >> 4, c41 = (tid & 15) * 4;

    float acc[2][2] = {};

    float4 pa0 = *(const float4*)&P[(i0+rr0)*512 + 0 + c40];
    float4 pa1 = *(const float4*)&P[(i0+rr1)*512 + 0 + c41];
    float4 pb0 = *(const float4*)&P[(j0+rr0)*512 + 256 + 0 + c40];
    float4 pb1 = *(const float4*)&P[(j0+rr1)*512 + 256 + 0 + c41];

    for (int c = 0; c < 4; ++c) {
        __syncthreads();
        *(float4*)&As[rr0][c40] = pa0;
        *(float4*)&As[rr1][c41] = pa1;
        Bs[c40+0][rr0] = pb0.x; Bs[c40+1][rr0] = pb0.y;
        Bs[c40+2][rr0] = pb0.z; Bs[c40+3][rr0] = pb0.w;
        Bs[c41+0][rr1] = pb1.x; Bs[c41+1][rr1] = pb1.y;
        Bs[c41+2][rr1] = pb1.z; Bs[c41+3][rr1] = pb1.w;
        __syncthreads();
        if (c + 1 < 4) {
            int h0 = (c+1) * 64;
            pa0 = *(const float4*)&P[(i0+rr0)*512 + h0 + c40];
            pa1 = *(const float4*)&P[(i0+rr1)*512 + h0 + c41];
            pb0 = *(const float4*)&P[(j0+rr0)*512 + 256 + h0 + c40];
            pb1 = *(const float4*)&P[(j0+rr1)*512 + 256 + h0 + c41];
        }

        for (int hh = 0; hh < 64; hh += 4) {
            float4 wv = *(const float4*)&wls[c*64 + hh];
            float4 a0 = *(const float4*)&As[ty*2+0][hh];
            float4 a1 = *(const float4*)&As[ty*2+1][hh];
            float2 b0 = *(const float2*)&Bs[hh+0][tx*2];
            float2 b1 = *(const float2*)&Bs[hh+1][tx*2];
            float2 b2 = *(const float2*)&Bs[hh+2][tx*2];
            float2 b3 = *(const float2*)&Bs[hh+3][tx*2];
            float aa[2][4] = {{a0.x,a0.y,a0.z,a0.w},{a1.x,a1.y,a1.z,a1.w}};
            float bb[4][2] = {{b0.x,b0.y},{b1.x,b1.y},{b2.x,b2.y},{b3.x,b3.y}};
            float ww[4] = {wv.x, wv.y, wv.z, wv.w};
            #pragma unroll
            for (int h = 0; h < 4; ++h)
                #pragma unroll
                for (int r = 0; r < 2; ++r)
                    #pragma unroll
                    for (int q = 0; q < 2; ++q) {
                        float u = fmaf(aa[r][h], bb[h][q], 1.0f);
                        acc[r][q] = fmaf(ww[h], frcp(u), acc[r][q]);
                    }
        }
    }

    float sumw = 0.0f;
    #pragma unroll
    for (int h = 0; h < 256; h += 4) {
        float4 wv = *(const float4*)&wls[h];
        sumw += (wv.x + wv.y) + (wv.z + wv.w);
    }
    const float base = ob[0] + sumw;
    const int row = i0 + ty*2;
    const int col = j0 + tx*2;
    #pragma unroll
    for (int r = 0; r < 2; ++r) {
        float2 o;
        o.x = base - 2.0f*acc[r][0];
        o.y = base - 2.0f*acc[r][1];
        *(float2*)&out[(row+r)*1024 + col] = o;
    }
}

extern "C" void kernel_launch(void* const* d_in, const int* in_sizes, int n_in,
                              void* d_out, int out_size, void* d_ws, size_t ws_size,
                              hipStream_t stream) {
    const float* l0   = (const float*)d_in[0];
    const float* l1   = (const float*)d_in[1];
    const float* Wfoh = (const float*)d_in[2];
    const float* Wfom = (const float*)d_in[3];
    const float* cb   = (const float*)d_in[4];
    const float* W2   = (const float*)d_in[5];
    const float* h2b  = (const float*)d_in[6];
    const float* w    = (const float*)d_in[7];
    const float* ob   = (const float*)d_in[8];
    float* out = (float*)d_out;

    unsigned int*   hv     = (unsigned int*)d_ws;
    float*          P      = (float*)(hv + 1024*1024);
    unsigned short* xs_hi  = (unsigned short*)(P + 1024*512);
    unsigned short* xs_lo  = xs_hi  + 1024*512;
    unsigned short* w1t_hi = xs_lo  + 1024*512;
    unsigned short* w1t_lo = w1t_hi + 1024*512;
    unsigned short* w2t_hi = w1t_lo + 1024*512;
    unsigned short* w2t_lo = w2t_hi + 256*1024;

    prep_all<<<1280, 256, 0, stream>>>(l0, l1, Wfoh, Wfom, W2,
                                       xs_hi, xs_lo, w1t_hi, w1t_lo, w2t_hi, w2t_lo);
    k1_mfma<<<256, 512, 0, stream>>>(xs_hi, xs_lo, w1t_hi, w1t_lo, cb, hv);
    k2_mfma<<<256, 512, 0, stream>>>(hv, w2t_hi, w2t_lo, h2b, P);
    k3_pairwise<<<dim3(32,32), 256, 0, stream>>>(P, w, ob, out);
}

// Round 8
// 156.129 us; speedup vs baseline: 1.2221x; 1.2221x over previous
//
#include <hip/hip_runtime.h>
#include <hip/hip_bf16.h>

typedef short s16x8 __attribute__((ext_vector_type(8)));
typedef float f32x4 __attribute__((ext_vector_type(4)));

#define LOG2E_2 2.8853900817779268f  // 2*log2(e)

__device__ __forceinline__ float fexp2(float x){ return __builtin_amdgcn_exp2f(x); }
__device__ __forceinline__ float frcp (float x){ return __builtin_amdgcn_rcpf(x); }
// tanh(v) = 1 - 2/(1+exp(2v))
__device__ __forceinline__ float ftanh(float v){
    return 1.0f - 2.0f * frcp(1.0f + fexp2(LOG2E_2 * v));
}
__device__ __forceinline__ unsigned short f2bf(float v){
    __hip_bfloat16 h = __float2bfloat16(v);
    return __builtin_bit_cast(unsigned short, h);
}
__device__ __forceinline__ float bf2f(unsigned short u){
    return __bfloat162float(__builtin_bit_cast(__hip_bfloat16, u));
}
__device__ __forceinline__ f32x4 mfma32(s16x8 a, s16x8 b, f32x4 c){
    return __builtin_amdgcn_mfma_f32_16x16x32_bf16(a, b, c, 0, 0, 0);
}

// ---------- prep_all: one launch does all reformatting ----------
__global__ __launch_bounds__(256) void prep_all(
    const float* __restrict__ l0, const float* __restrict__ l1,
    const float* __restrict__ Wfoh, const float* __restrict__ Wfom,
    const float* __restrict__ W2,
    unsigned short* __restrict__ xs_hi, unsigned short* __restrict__ xs_lo,
    unsigned short* __restrict__ w1t_hi, unsigned short* __restrict__ w1t_lo,
    unsigned short* __restrict__ w2t_hi, unsigned short* __restrict__ w2t_lo)
{
    const int b = blockIdx.x;
    const int t = threadIdx.x;
    if (b < 512) {
        int idx = (b*256 + t) * 4;
        int r = idx >> 9, c = idx & 511;
        float4 v = (c < 256) ? *(const float4*)(l0 + r*256 + c)
                             : *(const float4*)(l1 + r*256 + (c - 256));
        ushort4 h, l;
        h.x = f2bf(v.x); l.x = f2bf(v.x - bf2f(h.x));
        h.y = f2bf(v.y); l.y = f2bf(v.y - bf2f(h.y));
        h.z = f2bf(v.z); l.z = f2bf(v.z - bf2f(h.z));
        h.w = f2bf(v.w); l.w = f2bf(v.w - bf2f(h.w));
        *(ushort4*)(xs_hi + idx) = h;
        *(ushort4*)(xs_lo + idx) = l;
        return;
    }
    __shared__ float F[32][33];
    int k0, n0, K;
    const float *srcA, *srcB;
    int splitN, lda;
    unsigned short *dhi, *dlo;
    if (b < 1024) {
        int tb = b - 512;
        k0 = (tb & 15) * 32; n0 = (tb >> 4) * 32; K = 512;
        srcA = Wfoh; srcB = Wfom; splitN = 512; lda = 512;
        dhi = w1t_hi; dlo = w1t_lo;
    } else {
        int tb = b - 1024;
        k0 = (tb & 31) * 32; n0 = (tb >> 5) * 32; K = 1024;
        srcA = W2; srcB = W2; splitN = 1 << 30; lda = 256;
        dhi = w2t_hi; dlo = w2t_lo;
    }
    {
        int kk = t >> 3, n4 = (t & 7) * 4;
        int n = n0 + n4;
        const float* s = (n < splitN) ? (srcA + (k0+kk)*lda + n)
                                      : (srcB + (k0+kk)*lda + (n - splitN));
        float4 v = *(const float4*)s;
        F[kk][n4+0] = v.x; F[kk][n4+1] = v.y; F[kk][n4+2] = v.z; F[kk][n4+3] = v.w;
    }
    __syncthreads();
    {
        int nn = t >> 3, k4 = (t & 7) * 4;
        ushort4 h, l;
        float v0 = F[k4+0][nn]; h.x = f2bf(v0); l.x = f2bf(v0 - bf2f(h.x));
        float v1 = F[k4+1][nn]; h.y = f2bf(v1); l.y = f2bf(v1 - bf2f(h.y));
        float v2 = F[k4+2][nn]; h.z = f2bf(v2); l.z = f2bf(v2 - bf2f(h.z));
        float v3 = F[k4+3][nn]; h.w = f2bf(v3); l.w = f2bf(v3 - bf2f(h.w));
        *(ushort4*)(dhi + (n0+nn)*K + k0 + k4) = h;
        *(ushort4*)(dlo + (n0+nn)*K + k0 + k4) = l;
    }
}

// ---------- K1: hv = tanh(x @ W1 + cb), split-bf16, 16x16x32 MFMA ----------
// Tile 32m x 32n, grid (32 nx, 32 my) = 1024 blocks = 4 blocks/CU, 256 thr (4 waves).
// Latency hidden by block-level TLP (K3-proven shape), not per-block pipelining.
__global__ __launch_bounds__(256) void k1_mfma(
    const unsigned short* __restrict__ xs_hi, const unsigned short* __restrict__ xs_lo,
    const unsigned short* __restrict__ w1t_hi, const unsigned short* __restrict__ w1t_lo,
    const float* __restrict__ cb, unsigned int* __restrict__ hv)
{
    __shared__ unsigned short Ah[2][32][40], Al[2][32][40], Bh[2][32][40], Bl[2][32][40];
    const int t = threadIdx.x;
    const int r0 = blockIdx.y * 32, c0 = blockIdx.x * 32;
    const int w = t >> 6, lane = t & 63;
    const int m = lane & 15, quad = lane >> 4;
    const int wm = (w & 1) * 16, wn = (w >> 1) * 16;

    // staging: mat 0=A(t<128)/1=B; each thread one (row,kseg) slot, hi+lo planes
    const int mat  = t >> 7;
    const int srow = (t & 127) >> 2;   // 0..31
    const int skof = (t & 3) * 8;      // 0,8,16,24
    const unsigned short* ghi = mat ? (w1t_hi + (c0+srow)*512 + skof)
                                    : (xs_hi  + (r0+srow)*512 + skof);
    const unsigned short* glo = mat ? (w1t_lo + (c0+srow)*512 + skof)
                                    : (xs_lo  + (r0+srow)*512 + skof);

    uint4 rh[2], rl[2];
    rh[0] = *(const uint4*)(ghi);      rl[0] = *(const uint4*)(glo);
    rh[1] = *(const uint4*)(ghi + 32); rl[1] = *(const uint4*)(glo + 32);

    if (mat) { *(uint4*)&Bh[0][srow][skof] = rh[0]; *(uint4*)&Bl[0][srow][skof] = rl[0]; }
    else     { *(uint4*)&Ah[0][srow][skof] = rh[0]; *(uint4*)&Al[0][srow][skof] = rl[0]; }
    __syncthreads();

    f32x4 acc = {0,0,0,0};

    for (int c = 0; c < 16; ++c) {
        const int s0 = c & 1, s1 = (c+1) & 1;
        if (c + 2 < 16) {
            rh[s0] = *(const uint4*)(ghi + (c+2)*32);
            rl[s0] = *(const uint4*)(glo + (c+2)*32);
        }
        {
            const int ko = quad*8;
            s16x8 ah = *(const s16x8*)&Ah[s0][wm+m][ko];
            s16x8 al = *(const s16x8*)&Al[s0][wm+m][ko];
            s16x8 bh = *(const s16x8*)&Bh[s0][wn+m][ko];
            s16x8 bl = *(const s16x8*)&Bl[s0][wn+m][ko];
            acc = mfma32(ah, bh, acc);
            acc = mfma32(ah, bl, acc);
            acc = mfma32(al, bh, acc);
        }
        if (c + 1 < 16) {
            if (mat) { *(uint4*)&Bh[s1][srow][skof] = rh[s1]; *(uint4*)&Bl[s1][srow][skof] = rl[s1]; }
            else     { *(uint4*)&Ah[s1][srow][skof] = rh[s1]; *(uint4*)&Al[s1][srow][skof] = rl[s1]; }
            __syncthreads();
        }
    }

    const int col = c0 + wn + m;
    const float bias = cb[col];
    #pragma unroll
    for (int reg = 0; reg < 4; ++reg) {
        const int row = r0 + wm + quad*4 + reg;
        float v = ftanh(acc[reg] + bias);
        unsigned short h = f2bf(v);
        unsigned short l = f2bf(v - bf2f(h));
        hv[row*1024 + col] = (unsigned int)h | ((unsigned int)l << 16);
    }
}

// ---------- K2: P[1024][512] = exp2(LOG2E_2*(hv_half @ W2_half + bias)) ----------
// Tile 32m x 32n, grid (16 nx, 32 my) = 512 blocks = 2 blocks/CU, 256 thr (4 waves).
__global__ __launch_bounds__(256) void k2_mfma(
    const unsigned int* __restrict__ hv,
    const unsigned short* __restrict__ w2t_hi, const unsigned short* __restrict__ w2t_lo,
    const float* __restrict__ h2b, float* __restrict__ P)
{
    __shared__ unsigned short Ah[2][32][40], Al[2][32][40], Bh[2][32][40], Bl[2][32][40];
    const int t = threadIdx.x;
    const int r0 = blockIdx.y * 32, c0 = blockIdx.x * 32;
    const int half = (c0 >= 256) ? 1 : 0;
    const int ho = half * 512;
    const int nw = c0 & 255;
    const int w = t >> 6, lane = t & 63;
    const int m = lane & 15, quad = lane >> 4;
    const int wm = (w & 1) * 16, wn = (w >> 1) * 16;

    // A staging (all 256 thr): packed hv, row t>>3, k-off (t&7)*4 (4 u32)
    const int arow = t >> 3, akof = (t & 7) * 4;
    // B staging: t<128 -> hi plane, t>=128 -> lo plane; row (t&127)>>2, k-off (t&3)*8
    const int brow = (t & 127) >> 2, bkof = (t & 3) * 8;
    const int bmat = t >> 7;   // 0 = hi, 1 = lo

    const unsigned int*   gA = hv + (r0+arow)*1024 + ho + akof;
    const unsigned short* gB = (bmat ? w2t_lo : w2t_hi) + (nw+brow)*1024 + ho + bkof;

    uint4 ra[2], rb[2];
    ra[0] = *(const uint4*)(gA);      rb[0] = *(const uint4*)(gB);
    ra[1] = *(const uint4*)(gA + 32); rb[1] = *(const uint4*)(gB + 32);

    {
        ushort4 h = make_ushort4(ra[0].x & 0xffff, ra[0].y & 0xffff, ra[0].z & 0xffff, ra[0].w & 0xffff);
        ushort4 l = make_ushort4(ra[0].x >> 16,    ra[0].y >> 16,    ra[0].z >> 16,    ra[0].w >> 16);
        *(ushort4*)&Ah[0][arow][akof] = h;
        *(ushort4*)&Al[0][arow][akof] = l;
        if (bmat) *(uint4*)&Bl[0][brow][bkof] = rb[0];
        else      *(uint4*)&Bh[0][brow][bkof] = rb[0];
    }
    __syncthreads();

    f32x4 acc = {0,0,0,0};

    for (int c = 0; c < 16; ++c) {
        const int s0 = c & 1, s1 = (c+1) & 1;
        if (c + 2 < 16) {
            ra[s0] = *(const uint4*)(gA + (c+2)*32);
            rb[s0] = *(const uint4*)(gB + (c+2)*32);
        }
        {
            const int ko = quad*8;
            s16x8 ah = *(const s16x8*)&Ah[s0][wm+m][ko];
            s16x8 al = *(const s16x8*)&Al[s0][wm+m][ko];
            s16x8 bh = *(const s16x8*)&Bh[s0][wn+m][ko];
            s16x8 bl = *(const s16x8*)&Bl[s0][wn+m][ko];
            acc = mfma32(ah, bh, acc);
            acc = mfma32(ah, bl, acc);
            acc = mfma32(al, bh, acc);
        }
        if (c + 1 < 16) {
            ushort4 h = make_ushort4(ra[s1].x & 0xffff, ra[s1].y & 0xffff, ra[s1].z & 0xffff, ra[s1].w & 0xffff);
            ushort4 l = make_ushort4(ra[s1].x >> 16,    ra[s1].y >> 16,    ra[s1].z >> 16,    ra[s1].w >> 16);
            *(ushort4*)&Ah[s1][arow][akof] = h;
            *(ushort4*)&Al[s1][arow][akof] = l;
            if (bmat) *(uint4*)&Bl[s1][brow][bkof] = rb[s1];
            else      *(uint4*)&Bh[s1][brow][bkof] = rb[s1];
            __syncthreads();
        }
    }

    const int col = c0 + wn + m;
    const float bias = half ? 0.0f : h2b[col];
    #pragma unroll
    for (int reg = 0; reg < 4; ++reg) {
        const int row = r0 + wm + quad*4 + reg;
        P[row*512 + col] = fexp2((acc[reg] + bias) * LOG2E_2);
    }
}

// ---------- K3 (round-4 version, best known: 4 blocks/CU, 75% VALUBusy) ----------
__global__ __launch_bounds__(256) void k3_pairwise(
    const float* __restrict__ P, const float* __restrict__ w,
    const float* __restrict__ ob, float* __restrict__ out)
{
    __shared__ float As[32][68];
    __shared__ float Bs[64][34];
    __shared__ float wls[256];
    const int tid = threadIdx.x;
    const int tx = tid & 15;
    const int ty = tid >> 4;
    const int i0 = blockIdx.y * 32, j0 = blockIdx.x * 32;

    wls[tid] = w[tid];

    int rr0 = tid >> 4,         c40 = (tid & 15) * 4;
    int rr1 = (tid + 256) >> 4, c41 = (tid & 15) * 4;

    float acc[2][2] = {};

    float4 pa0 = *(const float4*)&P[(i0+rr0)*512 + 0 + c40];
    float4 pa1 = *(const float4*)&P[(i0+rr1)*512 + 0 + c41];
    float4 pb0 = *(const float4*)&P[(j0+rr0)*512 + 256 + 0 + c40];
    float4 pb1 = *(const float4*)&P[(j0+rr1)*512 + 256 + 0 + c41];

    for (int c = 0; c < 4; ++c) {
        __syncthreads();
        *(float4*)&As[rr0][c40] = pa0;
        *(float4*)&As[rr1][c41] = pa1;
        Bs[c40+0][rr0] = pb0.x; Bs[c40+1][rr0] = pb0.y;
        Bs[c40+2][rr0] = pb0.z; Bs[c40+3][rr0] = pb0.w;
        Bs[c41+0][rr1] = pb1.x; Bs[c41+1][rr1] = pb1.y;
        Bs[c41+2][rr1] = pb1.z; Bs[c41+3][rr1] = pb1.w;
        __syncthreads();
        if (c + 1 < 4) {
            int h0 = (c+1) * 64;
            pa0 = *(const float4*)&P[(i0+rr0)*512 + h0 + c40];
            pa1 = *(const float4*)&P[(i0+rr1)*512 + h0 + c41];
            pb0 = *(const float4*)&P[(j0+rr0)*512 + 256 + h0 + c40];
            pb1 = *(const float4*)&P[(j0+rr1)*512 + 256 + h0 + c41];
        }

        for (int hh = 0; hh < 64; hh += 4) {
            float4 wv = *(const float4*)&wls[c*64 + hh];
            float4 a0 = *(const float4*)&As[ty*2+0][hh];
            float4 a1 = *(const float4*)&As[ty*2+1][hh];
            float2 b0 = *(const float2*)&Bs[hh+0][tx*2];
            float2 b1 = *(const float2*)&Bs[hh+1][tx*2];
            float2 b2 = *(const float2*)&Bs[hh+2][tx*2];
            float2 b3 = *(const float2*)&Bs[hh+3][tx*2];
            float aa[2][4] = {{a0.x,a0.y,a0.z,a0.w},{a1.x,a1.y,a1.z,a1.w}};
            float bb[4][2] = {{b0.x,b0.y},{b1.x,b1.y},{b2.x,b2.y},{b3.x,b3.y}};
            float ww[4] = {wv.x, wv.y, wv.z, wv.w};
            #pragma unroll
            for (int h = 0; h < 4; ++h)
                #pragma unroll
                for (int r = 0; r < 2; ++r)
                    #pragma unroll
                    for (int q = 0; q < 2; ++q) {
                        float u = fmaf(aa[r][h], bb[h][q], 1.0f);
                        acc[r][q] = fmaf(ww[h], frcp(u), acc[r][q]);
                    }
        }
    }

    float sumw = 0.0f;
    #pragma unroll
    for (int h = 0; h < 256; h += 4) {
        float4 wv = *(const float4*)&wls[h];
        sumw += (wv.x + wv.y) + (wv.z + wv.w);
    }
    const float base = ob[0] + sumw;
    const int row = i0 + ty*2;
    const int col = j0 + tx*2;
    #pragma unroll
    for (int r = 0; r < 2; ++r) {
        float2 o;
        o.x = base - 2.0f*acc[r][0];
        o.y = base - 2.0f*acc[r][1];
        *(float2*)&out[(row+r)*1024 + col] = o;
    }
}

extern "C" void kernel_launch(void* const* d_in, const int* in_sizes, int n_in,
                              void* d_out, int out_size, void* d_ws, size_t ws_size,
                              hipStream_t stream) {
    const float* l0   = (const float*)d_in[0];
    const float* l1   = (const float*)d_in[1];
    const float* Wfoh = (const float*)d_in[2];
    const float* Wfom = (const float*)d_in[3];
    const float* cb   = (const float*)d_in[4];
    const float* W2   = (const float*)d_in[5];
    const float* h2b  = (const float*)d_in[6];
    const float* w    = (const float*)d_in[7];
    const float* ob   = (const float*)d_in[8];
    float* out = (float*)d_out;

    unsigned int*   hv     = (unsigned int*)d_ws;            // [1024][1024] u32
    float*          P      = (float*)(hv + 1024*1024);       // [1024][512] f32
    unsigned short* xs_hi  = (unsigned short*)(P + 1024*512);
    unsigned short* xs_lo  = xs_hi  + 1024*512;
    unsigned short* w1t_hi = xs_lo  + 1024*512;
    unsigned short* w1t_lo = w1t_hi + 1024*512;
    unsigned short* w2t_hi = w1t_lo + 1024*512;
    unsigned short* w2t_lo = w2t_hi + 256*1024;

    prep_all<<<1280, 256, 0, stream>>>(l0, l1, Wfoh, Wfom, W2,
                                       xs_hi, xs_lo, w1t_hi, w1t_lo, w2t_hi, w2t_lo);
    k1_mfma<<<dim3(32,32), 256, 0, stream>>>(xs_hi, xs_lo, w1t_hi, w1t_lo, cb, hv);
    k2_mfma<<<dim3(16,32), 256, 0, stream>>>(hv, w2t_hi, w2t_lo, h2b, P);
    k3_pairwise<<<dim3(32,32), 256, 0, stream>>>(P, w, ob, out);
}

// Round 9
// 131.036 us; speedup vs baseline: 1.4561x; 1.1915x over previous
//
#include <hip/hip_runtime.h>
#include <hip/hip_bf16.h>

typedef short s16x8 __attribute__((ext_vector_type(8)));
typedef float f32x4 __attribute__((ext_vector_type(4)));

#define LOG2E_2 2.8853900817779268f  // 2*log2(e)

__device__ __forceinline__ float fexp2(float x){ return __builtin_amdgcn_exp2f(x); }
__device__ __forceinline__ float frcp (float x){ return __builtin_amdgcn_rcpf(x); }
// tanh(v) = 1 - 2/(1+exp(2v))
__device__ __forceinline__ float ftanh(float v){
    return 1.0f - 2.0f * frcp(1.0f + fexp2(LOG2E_2 * v));
}
__device__ __forceinline__ unsigned short f2bf(float v){
    __hip_bfloat16 h = __float2bfloat16(v);
    return __builtin_bit_cast(unsigned short, h);
}
__device__ __forceinline__ f32x4 mfma32(s16x8 a, s16x8 b, f32x4 c){
    return __builtin_amdgcn_mfma_f32_16x16x32_bf16(a, b, c, 0, 0, 0);
}

// ---------- prep_w: transpose weights to bf16 [n][k] ----------
// blocks [0,512):   W1=[Wfoh|Wfom] [512k][1024n] -> w1t [1024][512]
// blocks [512,768): W2 [1024k][256n] -> w2t [256][1024]
__global__ __launch_bounds__(256) void prep_w(
    const float* __restrict__ Wfoh, const float* __restrict__ Wfom,
    const float* __restrict__ W2,
    unsigned short* __restrict__ w1t, unsigned short* __restrict__ w2t)
{
    __shared__ float F[32][33];
    const int b = blockIdx.x, t = threadIdx.x;
    int k0, n0, K, lda, splitN;
    const float *srcA, *srcB;
    unsigned short* dst;
    if (b < 512) {
        k0 = (b & 15) * 32; n0 = (b >> 4) * 32; K = 512;
        srcA = Wfoh; srcB = Wfom; splitN = 512; lda = 512; dst = w1t;
    } else {
        int tb = b - 512;
        k0 = (tb & 31) * 32; n0 = (tb >> 5) * 32; K = 1024;
        srcA = W2; srcB = W2; splitN = 1 << 30; lda = 256; dst = w2t;
    }
    {
        int kk = t >> 3, n4 = (t & 7) * 4;
        int n = n0 + n4;
        const float* s = (n < splitN) ? (srcA + (k0+kk)*lda + n)
                                      : (srcB + (k0+kk)*lda + (n - splitN));
        float4 v = *(const float4*)s;
        F[kk][n4+0] = v.x; F[kk][n4+1] = v.y; F[kk][n4+2] = v.z; F[kk][n4+3] = v.w;
    }
    __syncthreads();
    {
        int nn = t >> 3, k4 = (t & 7) * 4;
        ushort4 h;
        h.x = f2bf(F[k4+0][nn]);
        h.y = f2bf(F[k4+1][nn]);
        h.z = f2bf(F[k4+2][nn]);
        h.w = f2bf(F[k4+3][nn]);
        *(ushort4*)(dst + (n0+nn)*K + k0 + k4) = h;
    }
}

// ---------- K1: hv(bf16) = tanh(x @ W1 + cb), 1-term bf16 MFMA ----------
// Tile 32m x 32n, grid (32,32) = 1024 blocks = 4/CU, 256 thr (4 waves).
// BK=64 (8 chunks), double-buffered LDS + 2-slot register prefetch.
// x converted fp32->bf16 in the staging path (VALU is idle anyway).
__global__ __launch_bounds__(256) void k1_mfma(
    const float* __restrict__ l0, const float* __restrict__ l1,
    const unsigned short* __restrict__ w1t, const float* __restrict__ cb,
    unsigned short* __restrict__ hv)
{
    __shared__ unsigned short A[2][32][72], B[2][32][72];
    const int t = threadIdx.x;
    const int r0 = blockIdx.y*32, c0 = blockIdx.x*32;
    const int w = t>>6, lane = t&63, m = lane&15, quad = lane>>4;
    const int wm = (w&1)*16, wn = (w>>1)*16;
    const int srow = t>>3, sks = (t&7)*8;     // staging: row 0..31, k-off 0..56

    const unsigned short* gB = w1t + (c0+srow)*512 + sks;
    const float* ga0 = l0 + (r0+srow)*256;
    const float* ga1 = l1 + (r0+srow)*256;

    uint4 ra[2], rb[2];
    #pragma unroll
    for (int s = 0; s < 2; ++s) {
        int gk = s*64 + sks;
        const float* src = (gk < 256) ? (ga0 + gk) : (ga1 + gk - 256);
        float4 v0 = *(const float4*)src;
        float4 v1 = *(const float4*)(src + 4);
        ra[s].x = (unsigned)f2bf(v0.x) | ((unsigned)f2bf(v0.y) << 16);
        ra[s].y = (unsigned)f2bf(v0.z) | ((unsigned)f2bf(v0.w) << 16);
        ra[s].z = (unsigned)f2bf(v1.x) | ((unsigned)f2bf(v1.y) << 16);
        ra[s].w = (unsigned)f2bf(v1.z) | ((unsigned)f2bf(v1.w) << 16);
        rb[s] = *(const uint4*)(gB + s*64);
    }

    *(uint4*)&A[0][srow][sks] = ra[0];
    *(uint4*)&B[0][srow][sks] = rb[0];
    __syncthreads();

    f32x4 acc = {0,0,0,0};

    for (int c = 0; c < 8; ++c) {
        const int s0 = c & 1, s1 = (c+1) & 1;
        if (c + 2 < 8) {
            int gk = (c+2)*64 + sks;
            const float* src = (gk < 256) ? (ga0 + gk) : (ga1 + gk - 256);
            float4 v0 = *(const float4*)src;
            float4 v1 = *(const float4*)(src + 4);
            ra[s0].x = (unsigned)f2bf(v0.x) | ((unsigned)f2bf(v0.y) << 16);
            ra[s0].y = (unsigned)f2bf(v0.z) | ((unsigned)f2bf(v0.w) << 16);
            ra[s0].z = (unsigned)f2bf(v1.x) | ((unsigned)f2bf(v1.y) << 16);
            ra[s0].w = (unsigned)f2bf(v1.z) | ((unsigned)f2bf(v1.w) << 16);
            rb[s0] = *(const uint4*)(gB + (c+2)*64);
        }
        {
            const int ko = quad*8;
            s16x8 a0 = *(const s16x8*)&A[s0][wm+m][ko];
            s16x8 a1 = *(const s16x8*)&A[s0][wm+m][32+ko];
            s16x8 b0 = *(const s16x8*)&B[s0][wn+m][ko];
            s16x8 b1 = *(const s16x8*)&B[s0][wn+m][32+ko];
            acc = mfma32(a0, b0, acc);
            acc = mfma32(a1, b1, acc);
        }
        if (c + 1 < 8) {
            *(uint4*)&A[s1][srow][sks] = ra[s1];
            *(uint4*)&B[s1][srow][sks] = rb[s1];
            __syncthreads();
        }
    }

    const int col = c0 + wn + m;
    const float bias = cb[col];
    #pragma unroll
    for (int reg = 0; reg < 4; ++reg) {
        const int row = r0 + wm + quad*4 + reg;
        hv[row*1024 + col] = f2bf(ftanh(acc[reg] + bias));
    }
}

// ---------- K2: P[1024][512] = exp2(LOG2E_2*(hv_half @ W2_half + bias)) ----------
// Tile 32m x 32n, grid (16,32) = 512 blocks, 256 thr. Same pipeline as K1,
// A staged directly from bf16 hv (raw uint4 copies, no conversion).
__global__ __launch_bounds__(256) void k2_mfma(
    const unsigned short* __restrict__ hv, const unsigned short* __restrict__ w2t,
    const float* __restrict__ h2b, float* __restrict__ P)
{
    __shared__ unsigned short A[2][32][72], B[2][32][72];
    const int t = threadIdx.x;
    const int r0 = blockIdx.y*32, c0 = blockIdx.x*32;
    const int half = (c0 >= 256) ? 1 : 0;
    const int ho = half * 512;
    const int nw = c0 & 255;
    const int w = t>>6, lane = t&63, m = lane&15, quad = lane>>4;
    const int wm = (w&1)*16, wn = (w>>1)*16;
    const int srow = t>>3, sks = (t&7)*8;

    const unsigned short* gA = hv  + (r0+srow)*1024 + ho + sks;
    const unsigned short* gB = w2t + (nw+srow)*1024 + ho + sks;

    uint4 ra[2], rb[2];
    ra[0] = *(const uint4*)(gA);      rb[0] = *(const uint4*)(gB);
    ra[1] = *(const uint4*)(gA + 64); rb[1] = *(const uint4*)(gB + 64);

    *(uint4*)&A[0][srow][sks] = ra[0];
    *(uint4*)&B[0][srow][sks] = rb[0];
    __syncthreads();

    f32x4 acc = {0,0,0,0};

    for (int c = 0; c < 8; ++c) {
        const int s0 = c & 1, s1 = (c+1) & 1;
        if (c + 2 < 8) {
            ra[s0] = *(const uint4*)(gA + (c+2)*64);
            rb[s0] = *(const uint4*)(gB + (c+2)*64);
        }
        {
            const int ko = quad*8;
            s16x8 a0 = *(const s16x8*)&A[s0][wm+m][ko];
            s16x8 a1 = *(const s16x8*)&A[s0][wm+m][32+ko];
            s16x8 b0 = *(const s16x8*)&B[s0][wn+m][ko];
            s16x8 b1 = *(const s16x8*)&B[s0][wn+m][32+ko];
            acc = mfma32(a0, b0, acc);
            acc = mfma32(a1, b1, acc);
        }
        if (c + 1 < 8) {
            *(uint4*)&A[s1][srow][sks] = ra[s1];
            *(uint4*)&B[s1][srow][sks] = rb[s1];
            __syncthreads();
        }
    }

    const int col = c0 + wn + m;
    const float bias = half ? 0.0f : h2b[col];
    #pragma unroll
    for (int reg = 0; reg < 4; ++reg) {
        const int row = r0 + wm + quad*4 + reg;
        P[row*512 + col] = fexp2((acc[reg] + bias) * LOG2E_2);
    }
}

// ---------- K3 (round-4 proven version: 4 blocks/CU, ~75% VALUBusy) ----------
__global__ __launch_bounds__(256) void k3_pairwise(
    const float* __restrict__ P, const float* __restrict__ w,
    const float* __restrict__ ob, float* __restrict__ out)
{
    __shared__ float As[32][68];
    __shared__ float Bs[64][34];
    __shared__ float wls[256];
    const int tid = threadIdx.x;
    const int tx = tid & 15;
    const int ty = tid >> 4;
    const int i0 = blockIdx.y * 32, j0 = blockIdx.x * 32;

    wls[tid] = w[tid];

    int rr0 = tid >> 4,         c40 = (tid & 15) * 4;
    int rr1 = (tid + 256) >> 4, c41 = (tid & 15) * 4;

    float acc[2][2] = {};

    float4 pa0 = *(const float4*)&P[(i0+rr0)*512 + 0 + c40];
    float4 pa1 = *(const float4*)&P[(i0+rr1)*512 + 0 + c41];
    float4 pb0 = *(const float4*)&P[(j0+rr0)*512 + 256 + 0 + c40];
    float4 pb1 = *(const float4*)&P[(j0+rr1)*512 + 256 + 0 + c41];

    for (int c = 0; c < 4; ++c) {
        __syncthreads();
        *(float4*)&As[rr0][c40] = pa0;
        *(float4*)&As[rr1][c41] = pa1;
        Bs[c40+0][rr0] = pb0.x; Bs[c40+1][rr0] = pb0.y;
        Bs[c40+2][rr0] = pb0.z; Bs[c40+3][rr0] = pb0.w;
        Bs[c41+0][rr1] = pb1.x; Bs[c41+1][rr1] = pb1.y;
        Bs[c41+2][rr1] = pb1.z; Bs[c41+3][rr1] = pb1.w;
        __syncthreads();
        if (c + 1 < 4) {
            int h0 = (c+1) * 64;
            pa0 = *(const float4*)&P[(i0+rr0)*512 + h0 + c40];
            pa1 = *(const float4*)&P[(i0+rr1)*512 + h0 + c41];
            pb0 = *(const float4*)&P[(j0+rr0)*512 + 256 + h0 + c40];
            pb1 = *(const float4*)&P[(j0+rr1)*512 + 256 + h0 + c41];
        }

        for (int hh = 0; hh < 64; hh += 4) {
            float4 wv = *(const float4*)&wls[c*64 + hh];
            float4 a0 = *(const float4*)&As[ty*2+0][hh];
            float4 a1 = *(const float4*)&As[ty*2+1][hh];
            float2 b0 = *(const float2*)&Bs[hh+0][tx*2];
            float2 b1 = *(const float2*)&Bs[hh+1][tx*2];
            float2 b2 = *(const float2*)&Bs[hh+2][tx*2];
            float2 b3 = *(const float2*)&Bs[hh+3][tx*2];
            float aa[2][4] = {{a0.x,a0.y,a0.z,a0.w},{a1.x,a1.y,a1.z,a1.w}};
            float bb[4][2] = {{b0.x,b0.y},{b1.x,b1.y},{b2.x,b2.y},{b3.x,b3.y}};
            float ww[4] = {wv.x, wv.y, wv.z, wv.w};
            #pragma unroll
            for (int h = 0; h < 4; ++h)
                #pragma unroll
                for (int r = 0; r < 2; ++r)
                    #pragma unroll
                    for (int q = 0; q < 2; ++q) {
                        float u = fmaf(aa[r][h], bb[h][q], 1.0f);
                        acc[r][q] = fmaf(ww[h], frcp(u), acc[r][q]);
                    }
        }
    }

    float sumw = 0.0f;
    #pragma unroll
    for (int h = 0; h < 256; h += 4) {
        float4 wv = *(const float4*)&wls[h];
        sumw += (wv.x + wv.y) + (wv.z + wv.w);
    }
    const float base = ob[0] + sumw;
    const int row = i0 + ty*2;
    const int col = j0 + tx*2;
    #pragma unroll
    for (int r = 0; r < 2; ++r) {
        float2 o;
        o.x = base - 2.0f*acc[r][0];
        o.y = base - 2.0f*acc[r][1];
        *(float2*)&out[(row+r)*1024 + col] = o;
    }
}

extern "C" void kernel_launch(void* const* d_in, const int* in_sizes, int n_in,
                              void* d_out, int out_size, void* d_ws, size_t ws_size,
                              hipStream_t stream) {
    const float* l0   = (const float*)d_in[0];  // lstms0 [1024,256]
    const float* l1   = (const float*)d_in[1];  // lstms1 [1024,256]
    const float* Wfoh = (const float*)d_in[2];  // [512,512]
    const float* Wfom = (const float*)d_in[3];  // [512,512]
    const float* cb   = (const float*)d_in[4];  // [1024]
    const float* W2   = (const float*)d_in[5];  // [1024,256]
    const float* h2b  = (const float*)d_in[6];  // [256]
    const float* w    = (const float*)d_in[7];  // [256]
    const float* ob   = (const float*)d_in[8];  // [1]
    float* out = (float*)d_out;                 // [1024,1024]

    unsigned short* hv  = (unsigned short*)d_ws;      // [1024][1024] bf16 = 2 MB
    float*          P   = (float*)(hv + 1024*1024);   // [1024][512] f32  = 2 MB
    unsigned short* w1t = (unsigned short*)(P + 1024*512);  // [1024][512] bf16 = 1 MB
    unsigned short* w2t = w1t + 1024*512;                   // [256][1024] bf16 = 0.5 MB

    prep_w<<<768, 256, 0, stream>>>(Wfoh, Wfom, W2, w1t, w2t);
    k1_mfma<<<dim3(32,32), 256, 0, stream>>>(l0, l1, w1t, cb, hv);
    k2_mfma<<<dim3(16,32), 256, 0, stream>>>(hv, w2t, h2b, P);
    k3_pairwise<<<dim3(32,32), 256, 0, stream>>>(P, w, ob, out);
}